// Round 1
// baseline (1175.363 us; speedup 1.0000x reference)
//
#include <hip/hip_runtime.h>
#include <math.h>

#define BB 256
#define NF 512
#define IND 64
#define HD 128
#define SS 51
#define NHM1 63

// ws layout (float offsets):
// 0: lam, 1: xmax, 16..66: ccw, 80..130: u=(steps+1)/2,
// 144..399: xm, 400..655: xT, 656..911: out1, 1024..33791: c1[256][128]
#define WS_LAM  0
#define WS_XMAX 1
#define WS_CCW  16
#define WS_U    80
#define WS_XM   144
#define WS_XT   400
#define WS_OUT1 656
#define WS_C1   1024

__global__ void k_setup(const float* __restrict__ x_, const float* __restrict__ h_,
                        const float* __restrict__ W1, const float* __restrict__ b1,
                        const float* __restrict__ lw, const float* __restrict__ sp,
                        float* __restrict__ ws) {
    int b = blockIdx.x;
    int j = threadIdx.x;  // 128 threads

    // c1[b][j] = b1[j] + sum_k W1[j][1+k] * h_[b][k]
    float acc = b1[j];
    const float* w1row = W1 + j * IND;
    const float* hrow  = h_ + b * NHM1;
    #pragma unroll 7
    for (int k = 0; k < NHM1; ++k) acc = fmaf(w1row[1 + k], hrow[k], acc);
    ws[WS_C1 + b * HD + j] = acc;

    // xm[b] = sum_f x_[b][f] * lw[f]
    float s = 0.f;
    for (int k = j; k < NF; k += HD) s = fmaf(x_[b * NF + k], lw[k], s);
    __shared__ float red[HD];
    red[j] = s;
    __syncthreads();
    for (int off = 64; off > 0; off >>= 1) {
        if (j < off) red[j] += red[j + off];
        __syncthreads();
    }
    if (j == 0) ws[WS_XM + b] = red[0];

    if (b == 0) {
        if (j < SS) {
            // Clenshaw-Curtis weight i=j: cc[i] = sum_{jj even} lam[jj][i]*W[jj]
            float acc2 = 0.f;
            for (int jj = 0; jj <= 50; jj += 2) {
                float wj = (jj == 0) ? 1.f : 2.f / (1.f - (float)(jj * jj));
                float lamv;
                if (j == 0 || j == 50) {
                    lamv = 0.02f;  // j==0: 0.5*2/50; j==50: cos(jj*pi)=1 (jj even) *0.5*2/50
                } else {
                    int m = (jj * j) % 100;  // cos periodic with 100 units of pi/50
                    lamv = cosf((float)m * (float)M_PI / 50.f) * 0.04f;
                }
                acc2 = fmaf(lamv, wj, acc2);
            }
            ws[WS_CCW + j] = acc2;
            float st = cosf((float)j * (float)M_PI / 50.f);
            ws[WS_U + j] = (st + 1.f) * 0.5f;
        }
        if (j == 127) ws[WS_LAM] = 1.f / (1.f + expf(-sp[0]));
    }
}

__global__ void k_xt(const float* __restrict__ outprev, float* __restrict__ ws,
                     float* __restrict__ outnext, int use_out) {
    int t = threadIdx.x;  // 256 threads, 1 block
    float lam = ws[WS_LAM];
    float xm = ws[WS_XM + t];
    float x = (1.f - lam) * xm + (use_out ? lam * outprev[t] : 0.f);
    ws[WS_XT + t] = x;
    __shared__ float red[BB];
    red[t] = fmaxf(x, 0.f);
    __syncthreads();
    for (int off = 128; off > 0; off >>= 1) {
        if (t < off) red[t] = fmaxf(red[t], red[t + off]);
        __syncthreads();
    }
    if (t == 0) ws[WS_XMAX] = red[0] + 10.f;
    outnext[t] = 0.f;  // zero accumulator for the coming k_integral
}

__launch_bounds__(128, 2)
__global__ void k_integral(const float* __restrict__ W1, const float* __restrict__ W2,
                           const float* __restrict__ b2, const float* __restrict__ W3,
                           const float* __restrict__ b3, const float* __restrict__ fw,
                           const float* __restrict__ ws, float* __restrict__ out) {
    int bid = blockIdx.x;
    int s = bid % SS;
    int b = bid / SS;
    int j = threadIdx.x;  // 128 threads: one hidden neuron each

    float xmax = ws[WS_XMAX];
    float xT = ws[WS_XT + b];
    float x = xT * ws[WS_U + s];
    float range = xmax - x;

    float c1j  = ws[WS_C1 + b * HD + j];
    float w1tj = W1[j * IND];       // column 0 of W1 row j (the t weight)
    float b2j  = b2[j];
    float w3j  = W3[j];
    float b3v  = b3[0];
    float fw0 = fw[0], fw1 = fw[1], fw2 = fw[2], fw3 = fw[3], fw4 = fw[4];

    // cache W2 row j in registers: 32 x float4 = 128 VGPR
    float4 w2r[32];
    const float4* w2p = reinterpret_cast<const float4*>(W2 + j * HD);
    #pragma unroll
    for (int k = 0; k < 32; ++k) w2r[k] = w2p[k];

    __shared__ float4 a1v[HD / 4];
    __shared__ float red2[2];
    float accInner = 0.f;

    for (int si = 0; si < SS; ++si) {
        float t = fmaf(range, ws[WS_U + si], x);
        // layer 1 (folded): a1[j] = relu(c1[b][j] + w1t[j]*t)
        float a1 = fmaxf(fmaf(w1tj, t, c1j), 0.f);
        reinterpret_cast<float*>(a1v)[j] = a1;
        __syncthreads();
        // layer 2: a2[j] = relu(W2[j]·a1 + b2[j])
        float4 acc = {0.f, 0.f, 0.f, 0.f};
        #pragma unroll
        for (int k = 0; k < 32; ++k) {
            float4 av = a1v[k];
            acc.x = fmaf(w2r[k].x, av.x, acc.x);
            acc.y = fmaf(w2r[k].y, av.y, acc.y);
            acc.z = fmaf(w2r[k].z, av.z, acc.z);
            acc.w = fmaf(w2r[k].w, av.w, acc.w);
        }
        float a2 = fmaxf((acc.x + acc.y) + (acc.z + acc.w) + b2j, 0.f);
        // layer 3 partial: dot(a2, W3)
        float r = a2 * w3j;
        #pragma unroll
        for (int off = 32; off > 0; off >>= 1) r += __shfl_down(r, off);
        if ((j & 63) == 0) red2[j >> 6] = r;
        __syncthreads();
        if (j == 0) {
            float zpre = red2[0] + red2[1] + b3v;
            // z = elu(zpre) + 1
            float z = zpre > 0.f ? zpre + 1.f : expf(zpre);
            float sq = sqrtf(z);
            float p15 = z * sq;
            float p2  = z * z;
            float p25 = p2 * sq;
            float p3  = p2 * z;
            float p35 = p3 * sq;
            float g = fw0 / (p15 + 1.f) + fw1 / (p2 + 1.f) + fw2 / (p25 + 1.f)
                    + fw3 / (p3 + 1.f) + fw4 / (p35 + 1.f);
            g = fmaxf(g, 0.f);
            accInner = fmaf(g, ws[WS_CCW + si], accInner);
        }
    }
    if (j == 0) {
        float zin = accInner * range * 0.5f;             // inner integral value f(b,s)
        atomicAdd(&out[b], zin * ws[WS_CCW + s] * xT * 0.5f);
    }
}

extern "C" void kernel_launch(void* const* d_in, const int* in_sizes, int n_in,
                              void* d_out, int out_size, void* d_ws, size_t ws_size,
                              hipStream_t stream) {
    (void)in_sizes; (void)n_in; (void)out_size; (void)ws_size;
    const float* x_ = (const float*)d_in[0];
    const float* h_ = (const float*)d_in[1];
    const float* W1 = (const float*)d_in[2];
    const float* b1 = (const float*)d_in[3];
    const float* W2 = (const float*)d_in[4];
    const float* b2 = (const float*)d_in[5];
    const float* W3 = (const float*)d_in[6];
    const float* b3 = (const float*)d_in[7];
    const float* fw = (const float*)d_in[8];
    const float* lw = (const float*)d_in[9];
    const float* sp = (const float*)d_in[10];
    float* wsf  = (float*)d_ws;
    float* out1 = wsf + WS_OUT1;
    float* out  = (float*)d_out;

    k_setup<<<BB, HD, 0, stream>>>(x_, h_, W1, b1, lw, sp, wsf);
    // RNN step 0: xT = (1-lam)*xm; out1 = outer_integral(xT)
    k_xt<<<1, BB, 0, stream>>>(out1, wsf, out1, 0);
    k_integral<<<BB * SS, HD, 0, stream>>>(W1, W2, b2, W3, b3, fw, wsf, out1);
    // RNN step 1: xT = (1-lam)*xm + lam*out1; out = outer_integral(xT)
    k_xt<<<1, BB, 0, stream>>>(out1, wsf, out, 1);
    k_integral<<<BB * SS, HD, 0, stream>>>(W1, W2, b2, W3, b3, fw, wsf, out);
}

// Round 2
// 240.455 us; speedup vs baseline: 4.8881x; 4.8881x over previous
//
#include <hip/hip_runtime.h>
#include <math.h>

#define BB 256
#define NF 512
#define IND 64
#define HD 128
#define SS 51
#define NHM1 63

// ws layout (float offsets):
// 0: lam, 1: xmax, 16..66: ccw, 80..130: u=(steps+1)/2,
// 144..399: xm, 400..655: xT, 656..911: out1, 1024..33791: c1[256][128],
// 36864..45055: W2 f16 fragment table (16384 shorts)
#define WS_LAM  0
#define WS_XMAX 1
#define WS_CCW  16
#define WS_U    80
#define WS_XM   144
#define WS_XT   400
#define WS_OUT1 656
#define WS_C1   1024
#define WS_W2F  36864

typedef _Float16 f16x8 __attribute__((ext_vector_type(8)));
typedef float    f32x16 __attribute__((ext_vector_type(16)));

__global__ void k_setup(const float* __restrict__ x_, const float* __restrict__ h_,
                        const float* __restrict__ W1, const float* __restrict__ b1,
                        const float* __restrict__ W2, const float* __restrict__ lw,
                        const float* __restrict__ sp, float* __restrict__ ws) {
    int b = blockIdx.x;
    int j = threadIdx.x;  // 128 threads

    // c1[b][j] = b1[j] + sum_k W1[j][1+k] * h_[b][k]
    float acc = b1[j];
    const float* w1row = W1 + j * IND;
    const float* hrow  = h_ + b * NHM1;
    #pragma unroll 7
    for (int k = 0; k < NHM1; ++k) acc = fmaf(w1row[1 + k], hrow[k], acc);
    ws[WS_C1 + b * HD + j] = acc;

    // xm[b] = sum_f x_[b][f] * lw[f]
    float s = 0.f;
    for (int k = j; k < NF; k += HD) s = fmaf(x_[b * NF + k], lw[k], s);
    __shared__ float red[HD];
    red[j] = s;
    __syncthreads();
    for (int off = 64; off > 0; off >>= 1) {
        if (j < off) red[j] += red[j + off];
        __syncthreads();
    }
    if (j == 0) ws[WS_XM + b] = red[0];

    if (b == 0) {
        if (j < SS) {
            float acc2 = 0.f;
            for (int jj = 0; jj <= 50; jj += 2) {
                float wj = (jj == 0) ? 1.f : 2.f / (1.f - (float)(jj * jj));
                float lamv;
                if (j == 0 || j == 50) {
                    lamv = 0.02f;
                } else {
                    int m = (jj * j) % 100;
                    lamv = cosf((float)m * (float)M_PI / 50.f) * 0.04f;
                }
                acc2 = fmaf(lamv, wj, acc2);
            }
            ws[WS_CCW + j] = acc2;
            float st = cosf((float)j * (float)M_PI / 50.f);
            ws[WS_U + j] = (st + 1.f) * 0.5f;
        }
        if (j == 127) ws[WS_LAM] = 1.f / (1.f + expf(-sp[0]));
    }

    if (b == 1) {
        // pack W2 (fp32 [128][128]) into f16 MFMA B-fragment layout:
        // frag element (kk,nt,lane,i) = W2[nt*32+(lane&31)][kk*16+(lane>>5)*8+i]
        short* dst = (short*)(ws + WS_W2F);
        int row = j;  // W2 row = output neuron j
        const float* src = W2 + row * HD;
        int nt = row >> 5;
        int lanelo = row & 31;
        for (int k = 0; k < HD; ++k) {
            _Float16 hv = (_Float16)src[k];
            short sv; __builtin_memcpy(&sv, &hv, 2);
            int kk = k >> 4, hsel = (k >> 3) & 1, i = k & 7;
            dst[((kk * 4 + nt) * 64 + (lanelo + hsel * 32)) * 8 + i] = sv;
        }
    }
}

__global__ void k_xt(const float* __restrict__ outprev, float* __restrict__ ws,
                     float* __restrict__ outnext, int use_out) {
    int t = threadIdx.x;  // 256 threads, 1 block
    float lam = ws[WS_LAM];
    float xm = ws[WS_XM + t];
    float x = (1.f - lam) * xm + (use_out ? lam * outprev[t] : 0.f);
    ws[WS_XT + t] = x;
    __shared__ float red[BB];
    red[t] = fmaxf(x, 0.f);
    __syncthreads();
    for (int off = 128; off > 0; off >>= 1) {
        if (t < off) red[t] = fmaxf(red[t], red[t + off]);
        __syncthreads();
    }
    if (t == 0) ws[WS_XMAX] = red[0] + 10.f;
    outnext[t] = 0.f;  // zero accumulator for the coming k_integral
}

// One block = 4 waves, handles half of one batch row's 2601 evals.
// Per wave per iteration: one 32-eval M-tile.
//   A[32 x 128] = relu(c1 + w1t * t)  (f16, built in-register)
//   C[32 x 128] = A @ W2^T            (8 K-steps x 4 N-tiles of 32x32x16 MFMA)
//   z[m] = sum_j relu(C+b2)*w3  -> elu+1 -> power-features -> g -> acc += g*wgt
__launch_bounds__(256, 2)
__global__ void k_integral(const float* __restrict__ W1, const float* __restrict__ b2,
                           const float* __restrict__ W3, const float* __restrict__ b3,
                           const float* __restrict__ fw, const float* __restrict__ ws,
                           float* __restrict__ out) {
    int b = blockIdx.x >> 1, half = blockIdx.x & 1;
    int tid = threadIdx.x;
    int wv = tid >> 6, l = tid & 63;
    int c = l & 31, h = l >> 5;

    __shared__ __align__(16) float c1s[HD];
    __shared__ __align__(16) float w1s[HD];
    __shared__ float us[SS], ccs[SS];
    __shared__ float wgt_s[4][32];

    if (tid < HD) { c1s[tid] = ws[WS_C1 + b * HD + tid]; w1s[tid] = W1[tid * IND]; }
    if (tid < SS) { us[tid] = ws[WS_U + tid]; ccs[tid] = ws[WS_CCW + tid]; }
    __syncthreads();

    // stationary B fragments: 32 x f16x8 = 128 VGPR
    const f16x8* w2fv = reinterpret_cast<const f16x8*>(ws + WS_W2F);
    f16x8 Bf[8][4];
    #pragma unroll
    for (int kk = 0; kk < 8; ++kk)
        #pragma unroll
        for (int nt = 0; nt < 4; ++nt)
            Bf[kk][nt] = w2fv[(kk * 4 + nt) * 64 + l];

    float b2n[4], w3n[4];
    #pragma unroll
    for (int nt = 0; nt < 4; ++nt) { b2n[nt] = b2[nt * 32 + c]; w3n[nt] = W3[nt * 32 + c]; }
    float b3v = b3[0];
    float fw0 = fw[0], fw1 = fw[1], fw2 = fw[2], fw3 = fw[3], fw4 = fw[4];
    float xT = ws[WS_XT + b], xmax = ws[WS_XMAX];

    float accO = 0.f;

    for (int tl = half * 41 + wv; tl < half * 41 + 41; tl += 4) {
        int m = tl * 32 + c;                    // this lane's eval row in the A-tile
        int valid = (m <= 2600);
        int mm = valid ? m : 2600;
        int s  = (mm * 41121) >> 21;            // mm / 51 (magic, exact for mm < 110376)
        int si = mm - s * 51;
        float u_s = us[s], u_i = us[si];
        float x = xT * u_s;
        float range = xmax - x;
        float t = fmaf(range, u_i, x);
        float wgt = valid ? (ccs[si] * ccs[s] * range * xT * 0.25f) : 0.f;
        if (h == 0) wgt_s[wv][c] = wgt;

        f32x16 C[4];
        #pragma unroll
        for (int nt = 0; nt < 4; ++nt)
            #pragma unroll
            for (int e = 0; e < 16; ++e) C[nt][e] = 0.f;

        #pragma unroll
        for (int kk = 0; kk < 8; ++kk) {
            int k0 = kk * 16 + h * 8;
            float4 ca = *reinterpret_cast<const float4*>(&c1s[k0]);
            float4 cb = *reinterpret_cast<const float4*>(&c1s[k0 + 4]);
            float4 wa = *reinterpret_cast<const float4*>(&w1s[k0]);
            float4 wb = *reinterpret_cast<const float4*>(&w1s[k0 + 4]);
            f16x8 A;
            A[0] = (_Float16)fmaxf(fmaf(wa.x, t, ca.x), 0.f);
            A[1] = (_Float16)fmaxf(fmaf(wa.y, t, ca.y), 0.f);
            A[2] = (_Float16)fmaxf(fmaf(wa.z, t, ca.z), 0.f);
            A[3] = (_Float16)fmaxf(fmaf(wa.w, t, ca.w), 0.f);
            A[4] = (_Float16)fmaxf(fmaf(wb.x, t, cb.x), 0.f);
            A[5] = (_Float16)fmaxf(fmaf(wb.y, t, cb.y), 0.f);
            A[6] = (_Float16)fmaxf(fmaf(wb.z, t, cb.z), 0.f);
            A[7] = (_Float16)fmaxf(fmaf(wb.w, t, cb.w), 0.f);
            #pragma unroll
            for (int nt = 0; nt < 4; ++nt)
                C[nt] = __builtin_amdgcn_mfma_f32_32x32x16_f16(A, Bf[kk][nt], C[nt], 0, 0, 0);
        }

        // p[r] = partial z for row (r&3)+8*(r>>2)+4*h, summed over this lane's 4 j's
        float p[16];
        #pragma unroll
        for (int r = 0; r < 16; ++r) {
            float v = 0.f;
            #pragma unroll
            for (int nt = 0; nt < 4; ++nt) {
                float a2 = fmaxf(C[nt][r] + b2n[nt], 0.f);
                v = fmaf(a2, w3n[nt], v);
            }
            p[r] = v;
        }

        // compact halving butterfly over the 32-lane half: 16 rows x 32 cols -> row sums
        float q8[8];
        { int bit = (l >> 4) & 1;
          #pragma unroll
          for (int r = 0; r < 8; ++r) {
              float a = p[r], bb = p[r + 8];
              float mine = bit ? bb : a, oth = bit ? a : bb;
              q8[r] = mine + __shfl_xor(oth, 16, 64); } }
        float q4[4];
        { int bit = (l >> 3) & 1;
          #pragma unroll
          for (int r = 0; r < 4; ++r) {
              float a = q8[r], bb = q8[r + 4];
              float mine = bit ? bb : a, oth = bit ? a : bb;
              q4[r] = mine + __shfl_xor(oth, 8, 64); } }
        float q2[2];
        { int bit = (l >> 2) & 1;
          #pragma unroll
          for (int r = 0; r < 2; ++r) {
              float a = q4[r], bb = q4[r + 2];
              float mine = bit ? bb : a, oth = bit ? a : bb;
              q2[r] = mine + __shfl_xor(oth, 4, 64); } }
        float z1;
        { int bit = (l >> 1) & 1;
          float a = q2[0], bb = q2[1];
          float mine = bit ? bb : a, oth = bit ? a : bb;
          z1 = mine + __shfl_xor(oth, 2, 64); }
        z1 += __shfl_xor(z1, 1, 64);
        // now lane l holds full z-sum for reg r=(l>>1)&15 (rows duplicated in lane pairs)

        if (!(l & 1)) {
            int r = (l >> 1) & 15;
            int m_local = (r & 3) + 8 * (r >> 2) + 4 * h;
            float zs = z1 + b3v;
            float z = zs > 0.f ? zs + 1.f : __expf(zs);   // elu + 1
            float sq = sqrtf(z);
            float p15 = z * sq, p2 = z * z, p25 = p2 * sq, p3 = p2 * z, p35 = p3 * sq;
            float g = fw0 * __builtin_amdgcn_rcpf(p15 + 1.f)
                    + fw1 * __builtin_amdgcn_rcpf(p2  + 1.f)
                    + fw2 * __builtin_amdgcn_rcpf(p25 + 1.f)
                    + fw3 * __builtin_amdgcn_rcpf(p3  + 1.f)
                    + fw4 * __builtin_amdgcn_rcpf(p35 + 1.f);
            g = fmaxf(g, 0.f);
            accO = fmaf(g, wgt_s[wv][m_local], accO);
        }
    }

    #pragma unroll
    for (int off = 32; off >= 1; off >>= 1) accO += __shfl_xor(accO, off, 64);
    if (l == 0) atomicAdd(&out[b], accO);
}

extern "C" void kernel_launch(void* const* d_in, const int* in_sizes, int n_in,
                              void* d_out, int out_size, void* d_ws, size_t ws_size,
                              hipStream_t stream) {
    (void)in_sizes; (void)n_in; (void)out_size; (void)ws_size;
    const float* x_ = (const float*)d_in[0];
    const float* h_ = (const float*)d_in[1];
    const float* W1 = (const float*)d_in[2];
    const float* b1 = (const float*)d_in[3];
    const float* W2 = (const float*)d_in[4];
    const float* b2 = (const float*)d_in[5];
    const float* W3 = (const float*)d_in[6];
    const float* b3 = (const float*)d_in[7];
    const float* fw = (const float*)d_in[8];
    const float* lw = (const float*)d_in[9];
    const float* sp = (const float*)d_in[10];
    float* wsf  = (float*)d_ws;
    float* out1 = wsf + WS_OUT1;
    float* out  = (float*)d_out;

    k_setup<<<BB, HD, 0, stream>>>(x_, h_, W1, b1, W2, lw, sp, wsf);
    // RNN step 0: xT = (1-lam)*xm; out1 = outer_integral(xT)
    k_xt<<<1, BB, 0, stream>>>(out1, wsf, out1, 0);
    k_integral<<<BB * 2, 256, 0, stream>>>(W1, b2, W3, b3, fw, wsf, out1);
    // RNN step 1: xT = (1-lam)*xm + lam*out1; out = outer_integral(xT)
    k_xt<<<1, BB, 0, stream>>>(out1, wsf, out, 1);
    k_integral<<<BB * 2, 256, 0, stream>>>(W1, b2, W3, b3, fw, wsf, out);
}

// Round 3
// 140.148 us; speedup vs baseline: 8.3866x; 1.7157x over previous
//
#include <hip/hip_runtime.h>
#include <math.h>

#define BB 256
#define NF 512
#define IND 64
#define HD 128
#define SS 51
#define NHM1 63

// ws float offsets
#define WS_LAM  0
#define WS_XMAX 1
#define WS_CCW  16
#define WS_U    80
#define WS_XM   144
#define WS_XT   400
#define WS_OUT1 656
// ws half (short) offsets
#define WSH_C1  2048        // c1 f16 [256][128]
#define WSH_W1  34816       // w1t f16 [128]
#define WSH_W2F 40960       // W2 f16 fragment table [16384]
#define WS_W2F_F4 5120      // same, as float4 index (40960/8)

typedef _Float16 f16x8 __attribute__((ext_vector_type(8)));
typedef float    f32x16 __attribute__((ext_vector_type(16)));

__global__ void k_setup(const float* __restrict__ x_, const float* __restrict__ h_,
                        const float* __restrict__ W1, const float* __restrict__ b1,
                        const float* __restrict__ lw, const float* __restrict__ sp,
                        float* __restrict__ ws) {
    int b = blockIdx.x;
    int j = threadIdx.x;  // 128 threads
    short* wsh = (short*)ws;

    // c1[b][j] = b1[j] + sum_k W1[j][1+k] * h_[b][k]   (stored f16)
    float acc = b1[j];
    const float* w1row = W1 + j * IND;
    const float* hrow  = h_ + b * NHM1;
    #pragma unroll 7
    for (int k = 0; k < NHM1; ++k) acc = fmaf(w1row[1 + k], hrow[k], acc);
    {
        _Float16 hv = (_Float16)acc;
        short sv; __builtin_memcpy(&sv, &hv, 2);
        wsh[WSH_C1 + b * HD + j] = sv;
    }

    // xm[b] = sum_f x_[b][f] * lw[f]
    float s = 0.f;
    for (int k = j; k < NF; k += HD) s = fmaf(x_[b * NF + k], lw[k], s);
    __shared__ float red[HD];
    red[j] = s;
    __syncthreads();
    for (int off = 64; off > 0; off >>= 1) {
        if (j < off) red[j] += red[j + off];
        __syncthreads();
    }
    if (j == 0) ws[WS_XM + b] = red[0];

    if (b == 0) {
        if (j < SS) {
            float acc2 = 0.f;
            for (int jj = 0; jj <= 50; jj += 2) {
                float wj = (jj == 0) ? 1.f : 2.f / (1.f - (float)(jj * jj));
                float lamv;
                if (j == 0 || j == 50) {
                    lamv = 0.02f;
                } else {
                    int m = (jj * j) % 100;
                    lamv = cosf((float)m * (float)M_PI / 50.f) * 0.04f;
                }
                acc2 = fmaf(lamv, wj, acc2);
            }
            ws[WS_CCW + j] = acc2;
            float st = cosf((float)j * (float)M_PI / 50.f);
            ws[WS_U + j] = (st + 1.f) * 0.5f;
        }
        if (j == 127) ws[WS_LAM] = 1.f / (1.f + expf(-sp[0]));
    }
    if (b == 2) {
        // w1t column as f16
        _Float16 hv = (_Float16)W1[j * IND];
        short sv; __builtin_memcpy(&sv, &hv, 2);
        wsh[WSH_W1 + j] = sv;
    }
}

// pack W2 (fp32 [128][128]) into f16 MFMA B-fragment table:
// table[((kk*4+nt)*64 + lane)*8 + i] = f16(W2[nt*32+(lane&31)][kk*16+(lane>>5)*8+i])
__global__ void k_pack(const float* __restrict__ W2, float* __restrict__ ws) {
    int d = blockIdx.x * 256 + threadIdx.x;   // 0..16383
    int i = d & 7, lane = (d >> 3) & 63, kn = d >> 9;
    int kk = kn >> 2, nt = kn & 3;
    int row = nt * 32 + (lane & 31);
    int k = kk * 16 + (lane >> 5) * 8 + i;
    _Float16 hv = (_Float16)W2[row * HD + k];
    short sv; __builtin_memcpy(&sv, &hv, 2);
    ((short*)ws)[WSH_W2F + d] = sv;
}

__global__ void k_xt(const float* __restrict__ outprev, float* __restrict__ ws,
                     float* __restrict__ outnext, int use_out) {
    int t = threadIdx.x;  // 256 threads, 1 block
    float lam = ws[WS_LAM];
    float xm = ws[WS_XM + t];
    float x = (1.f - lam) * xm + (use_out ? lam * outprev[t] : 0.f);
    ws[WS_XT + t] = x;
    __shared__ float red[BB];
    red[t] = fmaxf(x, 0.f);
    __syncthreads();
    for (int off = 128; off > 0; off >>= 1) {
        if (t < off) red[t] = fmaxf(red[t], red[t + off]);
        __syncthreads();
    }
    if (t == 0) ws[WS_XMAX] = red[0] + 10.f;
    outnext[t] = 0.f;  // zero accumulator for the coming k_integral
}

// One block = 4 waves, half of one batch row's 2601 evals.
// Per wave-iteration: 64 evals = two 32-row A-tiles sharing each B fragment.
// B (W2 fragment table, 32 KB f16) lives in LDS; accumulators C[2][4] in VGPRs.
__launch_bounds__(256, 2)
__global__ void k_integral(const float* __restrict__ b2, const float* __restrict__ W3,
                           const float* __restrict__ b3, const float* __restrict__ fw,
                           const float* __restrict__ ws, float* __restrict__ out) {
    int b = blockIdx.x >> 1, half = blockIdx.x & 1;
    int tid = threadIdx.x;
    int wv = tid >> 6, l = tid & 63;
    int c = l & 31, h = l >> 5;

    __shared__ __align__(16) short w2s[16384];   // 32 KB fragment table
    __shared__ __align__(16) short c1s[HD];
    __shared__ __align__(16) short w1s[HD];
    __shared__ float us[SS], ccs[SS];
    __shared__ float wgt_s[4][64];

    // stage W2 fragments: 2048 float4s
    {
        const float4* src = reinterpret_cast<const float4*>(ws) + WS_W2F_F4;
        float4* dst = reinterpret_cast<float4*>(w2s);
        #pragma unroll
        for (int k = 0; k < 8; ++k) dst[tid + k * 256] = src[tid + k * 256];
    }
    if (tid < 16) {
        reinterpret_cast<float4*>(c1s)[tid] =
            reinterpret_cast<const float4*>((const short*)ws + WSH_C1 + b * HD)[tid];
    } else if (tid < 32) {
        reinterpret_cast<float4*>(w1s)[tid - 16] =
            reinterpret_cast<const float4*>((const short*)ws + WSH_W1)[tid - 16];
    }
    if (tid < SS) { us[tid] = ws[WS_U + tid]; ccs[tid] = ws[WS_CCW + tid]; }
    __syncthreads();

    const f16x8* w2v = reinterpret_cast<const f16x8*>(w2s);
    const f16x8* c1v = reinterpret_cast<const f16x8*>(c1s);
    const f16x8* w1v = reinterpret_cast<const f16x8*>(w1s);

    float b2n[4], w3n[4];
    #pragma unroll
    for (int nt = 0; nt < 4; ++nt) { b2n[nt] = b2[nt * 32 + c]; w3n[nt] = W3[nt * 32 + c]; }
    float b3v = b3[0];
    float fw0 = fw[0], fw1 = fw[1], fw2 = fw[2], fw3 = fw[3], fw4 = fw[4];
    float xT = ws[WS_XT + b], xmax = ws[WS_XMAX];

    float accO = 0.f;
    int start = half ? 21 : 0, end = half ? 41 : 21;

    for (int tl = start + wv; tl < end; tl += 4) {
        float t_[2];
        #pragma unroll
        for (int ti = 0; ti < 2; ++ti) {
            int m = tl * 64 + ti * 32 + c;
            int valid = (m <= 2600);
            int mm = valid ? m : 2600;
            int s  = (mm * 41121) >> 21;          // mm / 51 (exact for mm < 110376)
            int si = mm - s * 51;
            float x = xT * us[s];
            float range = xmax - x;
            t_[ti] = fmaf(range, us[si], x);
            float wgt = valid ? (ccs[si] * ccs[s] * range * xT * 0.25f) : 0.f;
            if (h == 0) wgt_s[wv][ti * 32 + c] = wgt;
        }
        _Float16 th0 = (_Float16)t_[0], th1 = (_Float16)t_[1];
        f16x8 tv0 = {th0, th0, th0, th0, th0, th0, th0, th0};
        f16x8 tv1 = {th1, th1, th1, th1, th1, th1, th1, th1};
        f16x8 zf = {};

        f32x16 C[2][4];
        #pragma unroll
        for (int ti = 0; ti < 2; ++ti)
            #pragma unroll
            for (int nt = 0; nt < 4; ++nt)
                #pragma unroll
                for (int e = 0; e < 16; ++e) C[ti][nt][e] = 0.f;

        #pragma unroll
        for (int kk = 0; kk < 8; ++kk) {
            f16x8 c1p = c1v[kk * 2 + h];
            f16x8 w1p = w1v[kk * 2 + h];
            f16x8 A0 = __builtin_elementwise_max(__builtin_elementwise_fma(w1p, tv0, c1p), zf);
            f16x8 A1 = __builtin_elementwise_max(__builtin_elementwise_fma(w1p, tv1, c1p), zf);
            #pragma unroll
            for (int nt = 0; nt < 4; ++nt) {
                f16x8 Bf = w2v[(kk * 4 + nt) * 64 + l];
                C[0][nt] = __builtin_amdgcn_mfma_f32_32x32x16_f16(A0, Bf, C[0][nt], 0, 0, 0);
                C[1][nt] = __builtin_amdgcn_mfma_f32_32x32x16_f16(A1, Bf, C[1][nt], 0, 0, 0);
            }
        }

        #pragma unroll
        for (int ti = 0; ti < 2; ++ti) {
            // p[r] = partial z for row crow(r,h), summed over this lane's 4 j's
            float p[16];
            #pragma unroll
            for (int r = 0; r < 16; ++r) {
                float v = 0.f;
                #pragma unroll
                for (int nt = 0; nt < 4; ++nt) {
                    float a2 = fmaxf(C[ti][nt][r] + b2n[nt], 0.f);
                    v = fmaf(a2, w3n[nt], v);
                }
                p[r] = v;
            }
            // halving butterfly over the 32-lane group: 16 rows x 32 cols -> row sums
            float q8[8];
            { int bit = (l >> 4) & 1;
              #pragma unroll
              for (int r = 0; r < 8; ++r) {
                  float a = p[r], bb = p[r + 8];
                  float mine = bit ? bb : a, oth = bit ? a : bb;
                  q8[r] = mine + __shfl_xor(oth, 16, 64); } }
            float q4[4];
            { int bit = (l >> 3) & 1;
              #pragma unroll
              for (int r = 0; r < 4; ++r) {
                  float a = q8[r], bb = q8[r + 4];
                  float mine = bit ? bb : a, oth = bit ? a : bb;
                  q4[r] = mine + __shfl_xor(oth, 8, 64); } }
            float q2[2];
            { int bit = (l >> 2) & 1;
              #pragma unroll
              for (int r = 0; r < 2; ++r) {
                  float a = q4[r], bb = q4[r + 2];
                  float mine = bit ? bb : a, oth = bit ? a : bb;
                  q2[r] = mine + __shfl_xor(oth, 4, 64); } }
            float z1;
            { int bit = (l >> 1) & 1;
              float a = q2[0], bb = q2[1];
              float mine = bit ? bb : a, oth = bit ? a : bb;
              z1 = mine + __shfl_xor(oth, 2, 64); }
            z1 += __shfl_xor(z1, 1, 64);
            // lane l (even) holds full z-sum for reg r=(l>>1)&15

            if (!(l & 1)) {
                int r = (l >> 1) & 15;
                int m_local = (r & 3) + 8 * (r >> 2) + 4 * h;
                float zs = z1 + b3v;
                float z = zs > 0.f ? zs + 1.f : __expf(zs);   // elu + 1
                float sq = sqrtf(z);
                float p15 = z * sq, p2 = z * z, p25 = p2 * sq, p3 = p2 * z, p35 = p3 * sq;
                float g = fw0 * __builtin_amdgcn_rcpf(p15 + 1.f)
                        + fw1 * __builtin_amdgcn_rcpf(p2  + 1.f)
                        + fw2 * __builtin_amdgcn_rcpf(p25 + 1.f)
                        + fw3 * __builtin_amdgcn_rcpf(p3  + 1.f)
                        + fw4 * __builtin_amdgcn_rcpf(p35 + 1.f);
                g = fmaxf(g, 0.f);
                accO = fmaf(g, wgt_s[wv][ti * 32 + m_local], accO);
            }
        }
    }

    #pragma unroll
    for (int off = 32; off >= 1; off >>= 1) accO += __shfl_xor(accO, off, 64);
    if (l == 0) atomicAdd(&out[b], accO);
}

extern "C" void kernel_launch(void* const* d_in, const int* in_sizes, int n_in,
                              void* d_out, int out_size, void* d_ws, size_t ws_size,
                              hipStream_t stream) {
    (void)in_sizes; (void)n_in; (void)out_size; (void)ws_size;
    const float* x_ = (const float*)d_in[0];
    const float* h_ = (const float*)d_in[1];
    const float* W1 = (const float*)d_in[2];
    const float* b1 = (const float*)d_in[3];
    const float* W2 = (const float*)d_in[4];
    const float* b2 = (const float*)d_in[5];
    const float* W3 = (const float*)d_in[6];
    const float* b3 = (const float*)d_in[7];
    const float* fw = (const float*)d_in[8];
    const float* lw = (const float*)d_in[9];
    const float* sp = (const float*)d_in[10];
    float* wsf  = (float*)d_ws;
    float* out1 = wsf + WS_OUT1;
    float* out  = (float*)d_out;

    k_setup<<<BB, HD, 0, stream>>>(x_, h_, W1, b1, lw, sp, wsf);
    k_pack<<<64, 256, 0, stream>>>(W2, wsf);
    // RNN step 0: xT = (1-lam)*xm; out1 = outer_integral(xT)
    k_xt<<<1, BB, 0, stream>>>(out1, wsf, out1, 0);
    k_integral<<<BB * 2, 256, 0, stream>>>(b2, W3, b3, fw, wsf, out1);
    // RNN step 1: xT = (1-lam)*xm + lam*out1; out = outer_integral(xT)
    k_xt<<<1, BB, 0, stream>>>(out1, wsf, out, 1);
    k_integral<<<BB * 2, 256, 0, stream>>>(b2, W3, b3, fw, wsf, out);
}

// Round 4
// 79.095 us; speedup vs baseline: 14.8601x; 1.7719x over previous
//
#include <hip/hip_runtime.h>
#include <math.h>

#define BB 256
#define NF 512
#define IND 64
#define HD 128
#define SS 51
#define NHM1 63

// ws float offsets
#define WS_LAM  0
#define WS_CCW  16
#define WS_U    80
#define WS_XM   144
#define WS_OUT1 656
// ws half (short) offsets
#define WSH_C1  2048        // c1 f16 [256][128]
#define WSH_W1  34816       // w1t f16 [128]
#define WSH_W2F 40960       // W2 f16 fragment table [16384]
#define WS_W2F_F4 5120      // same, as float4 index

typedef _Float16 f16x8 __attribute__((ext_vector_type(8)));
typedef float    f32x16 __attribute__((ext_vector_type(16)));

__global__ void k_setup(const float* __restrict__ x_, const float* __restrict__ h_,
                        const float* __restrict__ W1, const float* __restrict__ b1,
                        const float* __restrict__ W2, const float* __restrict__ lw,
                        const float* __restrict__ sp, float* __restrict__ ws) {
    int b = blockIdx.x;
    int j = threadIdx.x;  // 128 threads
    short* wsh = (short*)ws;

    // c1[b][j] = b1[j] + sum_k W1[j][1+k] * h_[b][k]   (stored f16)
    float acc = b1[j];
    const float* w1row = W1 + j * IND;
    const float* hrow  = h_ + b * NHM1;
    #pragma unroll 7
    for (int k = 0; k < NHM1; ++k) acc = fmaf(w1row[1 + k], hrow[k], acc);
    {
        _Float16 hv = (_Float16)acc;
        short sv; __builtin_memcpy(&sv, &hv, 2);
        wsh[WSH_C1 + b * HD + j] = sv;
    }

    // xm[b] = sum_f x_[b][f] * lw[f]
    float s = 0.f;
    for (int k = j; k < NF; k += HD) s = fmaf(x_[b * NF + k], lw[k], s);
    __shared__ float red[HD];
    red[j] = s;
    __syncthreads();
    for (int off = 64; off > 0; off >>= 1) {
        if (j < off) red[j] += red[j + off];
        __syncthreads();
    }
    if (j == 0) ws[WS_XM + b] = red[0];

    // W2 fragment pack: blocks 0..127 pack one element per thread
    // table[((kk*4+nt)*64 + lane)*8 + i] = f16(W2[nt*32+(lane&31)][kk*16+(lane>>5)*8+i])
    if (b < 128) {
        int d = b * 128 + j;   // 0..16383
        int i = d & 7, lane = (d >> 3) & 63, kn = d >> 9;
        int kk = kn >> 2, nt = kn & 3;
        int row = nt * 32 + (lane & 31);
        int k = kk * 16 + (lane >> 5) * 8 + i;
        _Float16 hv = (_Float16)W2[row * HD + k];
        short sv; __builtin_memcpy(&sv, &hv, 2);
        wsh[WSH_W2F + d] = sv;
    }

    if (b == 0) {
        if (j < SS) {
            float acc2 = 0.f;
            for (int jj = 0; jj <= 50; jj += 2) {
                float wj = (jj == 0) ? 1.f : 2.f / (1.f - (float)(jj * jj));
                float lamv;
                if (j == 0 || j == 50) {
                    lamv = 0.02f;
                } else {
                    int m = (jj * j) % 100;
                    lamv = cosf((float)m * (float)M_PI / 50.f) * 0.04f;
                }
                acc2 = fmaf(lamv, wj, acc2);
            }
            ws[WS_CCW + j] = acc2;
            float st = cosf((float)j * (float)M_PI / 50.f);
            ws[WS_U + j] = (st + 1.f) * 0.5f;
        }
        if (j == 127) ws[WS_LAM] = 1.f / (1.f + expf(-sp[0]));
    }
    if (b == 2) {
        _Float16 hv = (_Float16)W1[j * IND];   // w1t column as f16
        short sv; __builtin_memcpy(&sv, &hv, 2);
        wsh[WSH_W1 + j] = sv;
    }
    if (b == 4) ws[WS_OUT1 + j] = 0.f;
    if (b == 5) ws[WS_OUT1 + 128 + j] = 0.f;
}

// One block = 4 waves, half of one batch row's 2601 evals.
// Prologue replaces k_xt: all 256 threads compute xT over the batch + max-reduce.
// Per wave-iteration: 64 evals = two 32-row A-tiles sharing each B fragment.
// B (W2 fragment table, 32 KB f16) in LDS; C[2][4] accumulators (128 regs, AGPR).
// sched_barrier(0) per kk bounds ds_read hoisting so arch-VGPRs stay <=128 (no spill).
__launch_bounds__(256, 2)
__global__ void k_int(const float* __restrict__ b2, const float* __restrict__ W3,
                      const float* __restrict__ b3, const float* __restrict__ fw,
                      const float* __restrict__ ws, const float* __restrict__ outprev,
                      float* __restrict__ tgt, float* __restrict__ ztgt) {
    int b = blockIdx.x >> 1, half = blockIdx.x & 1;
    int tid = threadIdx.x;
    int wv = tid >> 6, l = tid & 63;
    int c = l & 31, h = l >> 5;

    __shared__ __align__(16) short w2s[16384];   // 32 KB fragment table
    __shared__ __align__(16) short c1s[HD];
    __shared__ __align__(16) short w1s[HD];
    __shared__ float us[SS], ccs[SS];
    __shared__ float wgt_s[4][64];
    __shared__ float xw[4];

    if (ztgt && half == 0 && tid == 0) ztgt[b] = 0.f;   // zero next-step accumulator

    // stage W2 fragments: 2048 float4s
    {
        const float4* src = reinterpret_cast<const float4*>(ws) + WS_W2F_F4;
        float4* dst = reinterpret_cast<float4*>(w2s);
        #pragma unroll
        for (int k = 0; k < 8; ++k) dst[tid + k * 256] = src[tid + k * 256];
    }
    if (tid < 16) {
        reinterpret_cast<float4*>(c1s)[tid] =
            reinterpret_cast<const float4*>((const short*)ws + WSH_C1 + b * HD)[tid];
    } else if (tid < 32) {
        reinterpret_cast<float4*>(w1s)[tid - 16] =
            reinterpret_cast<const float4*>((const short*)ws + WSH_W1)[tid - 16];
    }
    if (tid < SS) { us[tid] = ws[WS_U + tid]; ccs[tid] = ws[WS_CCW + tid]; }

    // xT / xmax prologue (replaces k_xt): xmax = max(0, max_b xT[b]) + 10
    float lam = ws[WS_LAM];
    float xmv = ws[WS_XM + tid];
    float opv = outprev ? outprev[tid] : 0.f;
    float xtv = (1.f - lam) * xmv + lam * opv;
    float mx = fmaxf(xtv, 0.f);
    #pragma unroll
    for (int off = 32; off >= 1; off >>= 1) mx = fmaxf(mx, __shfl_xor(mx, off, 64));
    if (l == 0) xw[wv] = mx;
    __syncthreads();
    float xmax = fmaxf(fmaxf(xw[0], xw[1]), fmaxf(xw[2], xw[3])) + 10.f;
    float xT = (1.f - lam) * ws[WS_XM + b] + lam * (outprev ? outprev[b] : 0.f);

    const f16x8* w2v = reinterpret_cast<const f16x8*>(w2s);
    const f16x8* c1v = reinterpret_cast<const f16x8*>(c1s);
    const f16x8* w1v = reinterpret_cast<const f16x8*>(w1s);

    float b2n[4], w3n[4];
    #pragma unroll
    for (int nt = 0; nt < 4; ++nt) { b2n[nt] = b2[nt * 32 + c]; w3n[nt] = W3[nt * 32 + c]; }
    float b3v = b3[0];
    float fw0 = fw[0], fw1 = fw[1], fw2 = fw[2], fw3 = fw[3], fw4 = fw[4];

    float accO = 0.f;
    int start = half ? 21 : 0, end = half ? 41 : 21;

    for (int tl = start + wv; tl < end; tl += 4) {
        float t_[2];
        #pragma unroll
        for (int ti = 0; ti < 2; ++ti) {
            int m = tl * 64 + ti * 32 + c;
            int valid = (m <= 2600);
            int mm = valid ? m : 2600;
            int s  = (mm * 41121) >> 21;          // mm / 51 (exact for mm < 110376)
            int si = mm - s * 51;
            float x = xT * us[s];
            float range = xmax - x;
            t_[ti] = fmaf(range, us[si], x);
            float wgt = valid ? (ccs[si] * ccs[s] * range * xT * 0.25f) : 0.f;
            if (h == 0) wgt_s[wv][ti * 32 + c] = wgt;
        }
        _Float16 th0 = (_Float16)t_[0], th1 = (_Float16)t_[1];
        f16x8 tv0 = {th0, th0, th0, th0, th0, th0, th0, th0};
        f16x8 tv1 = {th1, th1, th1, th1, th1, th1, th1, th1};
        f16x8 zf = {};

        f32x16 C[2][4];
        #pragma unroll
        for (int ti = 0; ti < 2; ++ti)
            #pragma unroll
            for (int nt = 0; nt < 4; ++nt)
                #pragma unroll
                for (int e = 0; e < 16; ++e) C[ti][nt][e] = 0.f;

        #pragma unroll
        for (int kk = 0; kk < 8; ++kk) {
            __builtin_amdgcn_sched_barrier(0);   // bound ds_read hoisting (spill guard)
            f16x8 c1p = c1v[kk * 2 + h];
            f16x8 w1p = w1v[kk * 2 + h];
            f16x8 A0 = __builtin_elementwise_max(__builtin_elementwise_fma(w1p, tv0, c1p), zf);
            f16x8 A1 = __builtin_elementwise_max(__builtin_elementwise_fma(w1p, tv1, c1p), zf);
            #pragma unroll
            for (int nt = 0; nt < 4; ++nt) {
                f16x8 Bf = w2v[(kk * 4 + nt) * 64 + l];
                C[0][nt] = __builtin_amdgcn_mfma_f32_32x32x16_f16(A0, Bf, C[0][nt], 0, 0, 0);
                C[1][nt] = __builtin_amdgcn_mfma_f32_32x32x16_f16(A1, Bf, C[1][nt], 0, 0, 0);
            }
        }
        __builtin_amdgcn_sched_barrier(0);

        #pragma unroll
        for (int ti = 0; ti < 2; ++ti) {
            float p[16];
            #pragma unroll
            for (int r = 0; r < 16; ++r) {
                float v = 0.f;
                #pragma unroll
                for (int nt = 0; nt < 4; ++nt) {
                    float a2 = fmaxf(C[ti][nt][r] + b2n[nt], 0.f);
                    v = fmaf(a2, w3n[nt], v);
                }
                p[r] = v;
            }
            // halving butterfly: 16 rows x 32 cols -> row sums
            float q8[8];
            { int bit = (l >> 4) & 1;
              #pragma unroll
              for (int r = 0; r < 8; ++r) {
                  float a = p[r], bb = p[r + 8];
                  float mine = bit ? bb : a, oth = bit ? a : bb;
                  q8[r] = mine + __shfl_xor(oth, 16, 64); } }
            float q4[4];
            { int bit = (l >> 3) & 1;
              #pragma unroll
              for (int r = 0; r < 4; ++r) {
                  float a = q8[r], bb = q8[r + 4];
                  float mine = bit ? bb : a, oth = bit ? a : bb;
                  q4[r] = mine + __shfl_xor(oth, 8, 64); } }
            float q2[2];
            { int bit = (l >> 2) & 1;
              #pragma unroll
              for (int r = 0; r < 2; ++r) {
                  float a = q4[r], bb = q4[r + 2];
                  float mine = bit ? bb : a, oth = bit ? a : bb;
                  q2[r] = mine + __shfl_xor(oth, 4, 64); } }
            float z1;
            { int bit = (l >> 1) & 1;
              float a = q2[0], bb = q2[1];
              float mine = bit ? bb : a, oth = bit ? a : bb;
              z1 = mine + __shfl_xor(oth, 2, 64); }
            z1 += __shfl_xor(z1, 1, 64);
            // lane l (even) holds full z-sum for reg r=(l>>1)&15

            if (!(l & 1)) {
                int r = (l >> 1) & 15;
                int m_local = (r & 3) + 8 * (r >> 2) + 4 * h;
                float zs = z1 + b3v;
                float z = zs > 0.f ? zs + 1.f : __expf(zs);   // elu + 1
                float sq = sqrtf(z);
                float p15 = z * sq, p2 = z * z, p25 = p2 * sq, p3 = p2 * z, p35 = p3 * sq;
                float g = fw0 * __builtin_amdgcn_rcpf(p15 + 1.f)
                        + fw1 * __builtin_amdgcn_rcpf(p2  + 1.f)
                        + fw2 * __builtin_amdgcn_rcpf(p25 + 1.f)
                        + fw3 * __builtin_amdgcn_rcpf(p3  + 1.f)
                        + fw4 * __builtin_amdgcn_rcpf(p35 + 1.f);
                g = fmaxf(g, 0.f);
                accO = fmaf(g, wgt_s[wv][ti * 32 + m_local], accO);
            }
        }
    }

    #pragma unroll
    for (int off = 32; off >= 1; off >>= 1) accO += __shfl_xor(accO, off, 64);
    if (l == 0) atomicAdd(&tgt[b], accO);
}

extern "C" void kernel_launch(void* const* d_in, const int* in_sizes, int n_in,
                              void* d_out, int out_size, void* d_ws, size_t ws_size,
                              hipStream_t stream) {
    (void)in_sizes; (void)n_in; (void)out_size; (void)ws_size;
    const float* x_ = (const float*)d_in[0];
    const float* h_ = (const float*)d_in[1];
    const float* W1 = (const float*)d_in[2];
    const float* b1 = (const float*)d_in[3];
    const float* W2 = (const float*)d_in[4];
    const float* b2 = (const float*)d_in[5];
    const float* W3 = (const float*)d_in[6];
    const float* b3 = (const float*)d_in[7];
    const float* fw = (const float*)d_in[8];
    const float* lw = (const float*)d_in[9];
    const float* sp = (const float*)d_in[10];
    float* wsf  = (float*)d_ws;
    float* out1 = wsf + WS_OUT1;
    float* out  = (float*)d_out;

    // setup: c1, xm, CC tables, lam, W2 fragment pack, zero out1
    k_setup<<<BB, HD, 0, stream>>>(x_, h_, W1, b1, W2, lw, sp, wsf);
    // RNN step 0: xT=(1-lam)*xm (outprev=null); accumulate into out1; zero d_out
    k_int<<<BB * 2, 256, 0, stream>>>(b2, W3, b3, fw, wsf, nullptr, out1, out);
    // RNN step 1: xT=(1-lam)*xm+lam*out1; accumulate into d_out
    k_int<<<BB * 2, 256, 0, stream>>>(b2, W3, b3, fw, wsf, out1, out, nullptr);
}

// Round 5
// 78.548 us; speedup vs baseline: 14.9635x; 1.0070x over previous
//
#include <hip/hip_runtime.h>
#include <math.h>

#define BB 256
#define NF 512
#define IND 64
#define HD 128
#define SS 51
#define NHM1 63

// ws float offsets
#define WS_LAM  0
#define WS_CCW  16
#define WS_U    80
#define WS_XM   144
#define WS_OUT1 656
// ws half (short) offsets
#define WSH_C1  2048        // c1 f16 [256][128]
#define WSH_W1  34816       // w1t f16 [128]
#define WSH_W2F 40960       // W2 f16 fragment table [16384]

typedef _Float16 f16x8 __attribute__((ext_vector_type(8)));
typedef float    f32x16 __attribute__((ext_vector_type(16)));

__global__ void k_setup(const float* __restrict__ x_, const float* __restrict__ h_,
                        const float* __restrict__ W1, const float* __restrict__ b1,
                        const float* __restrict__ W2, const float* __restrict__ lw,
                        const float* __restrict__ sp, float* __restrict__ ws) {
    int b = blockIdx.x;
    int j = threadIdx.x;  // 128 threads
    short* wsh = (short*)ws;

    // c1[b][j] = b1[j] + sum_k W1[j][1+k] * h_[b][k]   (stored f16)
    float acc = b1[j];
    const float* w1row = W1 + j * IND;
    const float* hrow  = h_ + b * NHM1;
    #pragma unroll 7
    for (int k = 0; k < NHM1; ++k) acc = fmaf(w1row[1 + k], hrow[k], acc);
    {
        _Float16 hv = (_Float16)acc;
        short sv; __builtin_memcpy(&sv, &hv, 2);
        wsh[WSH_C1 + b * HD + j] = sv;
    }

    // xm[b] = sum_f x_[b][f] * lw[f]
    float s = 0.f;
    for (int k = j; k < NF; k += HD) s = fmaf(x_[b * NF + k], lw[k], s);
    __shared__ float red[HD];
    red[j] = s;
    __syncthreads();
    for (int off = 64; off > 0; off >>= 1) {
        if (j < off) red[j] += red[j + off];
        __syncthreads();
    }
    if (j == 0) ws[WS_XM + b] = red[0];

    // W2 fragment pack (A/B-symmetric 32x32x16 layout):
    // table[((kk*4+nt)*64 + lane)*8 + i] = f16(W2[nt*32+(lane&31)][kk*16+(lane>>5)*8+i])
    if (b < 128) {
        int d = b * 128 + j;   // 0..16383
        int i = d & 7, lane = (d >> 3) & 63, kn = d >> 9;
        int kk = kn >> 2, nt = kn & 3;
        int row = nt * 32 + (lane & 31);
        int k = kk * 16 + (lane >> 5) * 8 + i;
        _Float16 hv = (_Float16)W2[row * HD + k];
        short sv; __builtin_memcpy(&sv, &hv, 2);
        wsh[WSH_W2F + d] = sv;
    }

    if (b == 0) {
        if (j < SS) {
            float acc2 = 0.f;
            for (int jj = 0; jj <= 50; jj += 2) {
                float wj = (jj == 0) ? 1.f : 2.f / (1.f - (float)(jj * jj));
                float lamv;
                if (j == 0 || j == 50) {
                    lamv = 0.02f;
                } else {
                    int m = (jj * j) % 100;
                    lamv = cosf((float)m * (float)M_PI / 50.f) * 0.04f;
                }
                acc2 = fmaf(lamv, wj, acc2);
            }
            ws[WS_CCW + j] = acc2;
            float st = cosf((float)j * (float)M_PI / 50.f);
            ws[WS_U + j] = (st + 1.f) * 0.5f;
        }
        if (j == 127) ws[WS_LAM] = 1.f / (1.f + expf(-sp[0]));
    }
    if (b == 2) {
        _Float16 hv = (_Float16)W1[j * IND];   // w1t column as f16
        short sv; __builtin_memcpy(&sv, &hv, 2);
        wsh[WSH_W1 + j] = sv;
    }
    if (b == 4) ws[WS_OUT1 + j] = 0.f;
    if (b == 5) ws[WS_OUT1 + 128 + j] = 0.f;
}

// One block = 4 waves cooperating: per block-iter, 64 evals x full 128 j.
// Wave wv owns j-tile [32wv, 32wv+32): A = W2 fragments STATIONARY in registers
// (8 x f16x8); B = a1 fragments built in-register from c1/w1 register slices + t.
// Main loop has zero LDS streaming; j-combine via 1KB double-buffered partials.
__launch_bounds__(256, 2)
__global__ void k_int(const float* __restrict__ b2, const float* __restrict__ W3,
                      const float* __restrict__ b3, const float* __restrict__ fw,
                      const float* __restrict__ ws, const float* __restrict__ outprev,
                      float* __restrict__ tgt, float* __restrict__ ztgt) {
    int b = blockIdx.x >> 1, half = blockIdx.x & 1;
    int tid = threadIdx.x;
    int wv = tid >> 6, l = tid & 63;
    int e32 = l & 31, h2 = l >> 5;

    __shared__ float us[SS], ccs[SS], xw[4];
    __shared__ float part[2][2][4][32];   // [buf][ti][wv][eval32]

    if (ztgt && half == 0 && tid == 0) ztgt[b] = 0.f;   // zero next-step accumulator
    if (tid < SS) { us[tid] = ws[WS_U + tid]; ccs[tid] = ws[WS_CCW + tid]; }

    // xT / xmax prologue: xmax = max(0, max_b xT[b]) + 10
    float lam = ws[WS_LAM];
    float xmv = ws[WS_XM + tid];
    float opv = outprev ? outprev[tid] : 0.f;
    float xtv = (1.f - lam) * xmv + lam * opv;
    float mx = fmaxf(xtv, 0.f);
    #pragma unroll
    for (int off = 32; off >= 1; off >>= 1) mx = fmaxf(mx, __shfl_xor(mx, off, 64));
    if (l == 0) xw[wv] = mx;
    __syncthreads();
    float xmax = fmaxf(fmaxf(xw[0], xw[1]), fmaxf(xw[2], xw[3])) + 10.f;
    float xT = (1.f - lam) * ws[WS_XM + b] + lam * (outprev ? outprev[b] : 0.f);

    const short* wsh = (const short*)ws;

    // stationary register state
    f16x8 Af[8], c1r[8], w1r[8];
    #pragma unroll
    for (int kk = 0; kk < 8; ++kk) {
        Af[kk]  = *reinterpret_cast<const f16x8*>(wsh + WSH_W2F + ((kk * 4 + wv) * 64 + l) * 8);
        c1r[kk] = *reinterpret_cast<const f16x8*>(wsh + WSH_C1 + b * HD + kk * 16 + h2 * 8);
        w1r[kk] = *reinterpret_cast<const f16x8*>(wsh + WSH_W1 + kk * 16 + h2 * 8);
    }
    float b2n[16], w3n[16];
    #pragma unroll
    for (int r = 0; r < 16; ++r) {
        int j = wv * 32 + (r & 3) + 8 * (r >> 2) + 4 * h2;   // D-row for reg r
        b2n[r] = b2[j]; w3n[r] = W3[j];
    }
    float b3v = b3[0];
    float fw0 = fw[0], fw1 = fw[1], fw2 = fw[2], fw3 = fw[3], fw4 = fw[4];

    float accO = 0.f;
    int buf = 0;
    int base0 = half * 1344;   // 21 iters * 64 evals

    for (int it = 0; it < 21; ++it) {
        int base = base0 + it * 64;
        float t_[2];
        #pragma unroll
        for (int ti = 0; ti < 2; ++ti) {
            int m = base + ti * 32 + e32;
            int mm = m <= 2600 ? m : 2600;
            int s  = (mm * 41121) >> 21;          // mm / 51 (exact for mm < 110376)
            int si = mm - s * 51;
            float x = xT * us[s];
            t_[ti] = fmaf(xmax - x, us[si], x);
        }
        _Float16 th0 = (_Float16)t_[0], th1 = (_Float16)t_[1];
        f16x8 tv0 = {th0, th0, th0, th0, th0, th0, th0, th0};
        f16x8 tv1 = {th1, th1, th1, th1, th1, th1, th1, th1};
        f16x8 zf = {};

        f32x16 C0, C1;
        #pragma unroll
        for (int e = 0; e < 16; ++e) { C0[e] = 0.f; C1[e] = 0.f; }

        #pragma unroll
        for (int kk = 0; kk < 8; ++kk) {
            f16x8 B0 = __builtin_elementwise_max(__builtin_elementwise_fma(w1r[kk], tv0, c1r[kk]), zf);
            f16x8 B1 = __builtin_elementwise_max(__builtin_elementwise_fma(w1r[kk], tv1, c1r[kk]), zf);
            C0 = __builtin_amdgcn_mfma_f32_32x32x16_f16(Af[kk], B0, C0, 0, 0, 0);
            C1 = __builtin_amdgcn_mfma_f32_32x32x16_f16(Af[kk], B1, C1, 0, 0, 0);
            __builtin_amdgcn_sched_barrier(0);
        }

        // per-wave j-partial: sum_r relu(C+b2)*w3, then fold h-halves
        {
            float s0 = 0.f;
            #pragma unroll
            for (int r = 0; r < 16; ++r) s0 = fmaf(fmaxf(C0[r] + b2n[r], 0.f), w3n[r], s0);
            s0 += __shfl_xor(s0, 32, 64);
            if (h2 == 0) part[buf][0][wv][e32] = s0;
            float s1 = 0.f;
            #pragma unroll
            for (int r = 0; r < 16; ++r) s1 = fmaf(fmaxf(C1[r] + b2n[r], 0.f), w3n[r], s1);
            s1 += __shfl_xor(s1, 32, 64);
            if (h2 == 0) part[buf][1][wv][e32] = s1;
        }
        __syncthreads();

        if (wv == 0) {   // scalar tail: lane l handles eval base + l
            int m = base + l;
            float zs = part[buf][h2][0][e32] + part[buf][h2][1][e32]
                     + part[buf][h2][2][e32] + part[buf][h2][3][e32] + b3v;
            float z = zs > 0.f ? zs + 1.f : __expf(zs);   // elu + 1
            float sq = sqrtf(z);
            float p15 = z * sq, p2 = z * z, p25 = p2 * sq, p3 = p2 * z, p35 = p3 * sq;
            float g = fw0 * __builtin_amdgcn_rcpf(p15 + 1.f)
                    + fw1 * __builtin_amdgcn_rcpf(p2  + 1.f)
                    + fw2 * __builtin_amdgcn_rcpf(p25 + 1.f)
                    + fw3 * __builtin_amdgcn_rcpf(p3  + 1.f)
                    + fw4 * __builtin_amdgcn_rcpf(p35 + 1.f);
            g = fmaxf(g, 0.f);
            int valid = (m <= 2600);
            int mm = valid ? m : 2600;
            int s  = (mm * 41121) >> 21;
            int si = mm - s * 51;
            float x = xT * us[s];
            float wgt = valid ? (ccs[si] * ccs[s] * (xmax - x) * xT * 0.25f) : 0.f;
            accO = fmaf(g, wgt, accO);
        }
        buf ^= 1;
    }

    if (wv == 0) {
        #pragma unroll
        for (int off = 32; off >= 1; off >>= 1) accO += __shfl_xor(accO, off, 64);
        if (l == 0) atomicAdd(&tgt[b], accO);
    }
}

extern "C" void kernel_launch(void* const* d_in, const int* in_sizes, int n_in,
                              void* d_out, int out_size, void* d_ws, size_t ws_size,
                              hipStream_t stream) {
    (void)in_sizes; (void)n_in; (void)out_size; (void)ws_size;
    const float* x_ = (const float*)d_in[0];
    const float* h_ = (const float*)d_in[1];
    const float* W1 = (const float*)d_in[2];
    const float* b1 = (const float*)d_in[3];
    const float* W2 = (const float*)d_in[4];
    const float* b2 = (const float*)d_in[5];
    const float* W3 = (const float*)d_in[6];
    const float* b3 = (const float*)d_in[7];
    const float* fw = (const float*)d_in[8];
    const float* lw = (const float*)d_in[9];
    const float* sp = (const float*)d_in[10];
    float* wsf  = (float*)d_ws;
    float* out1 = wsf + WS_OUT1;
    float* out  = (float*)d_out;

    // setup: c1, xm, CC tables, lam, W2 fragment pack, zero out1
    k_setup<<<BB, HD, 0, stream>>>(x_, h_, W1, b1, W2, lw, sp, wsf);
    // RNN step 0: xT=(1-lam)*xm (outprev=null); accumulate into out1; zero d_out
    k_int<<<BB * 2, 256, 0, stream>>>(b2, W3, b3, fw, wsf, nullptr, out1, out);
    // RNN step 1: xT=(1-lam)*xm+lam*out1; accumulate into d_out
    k_int<<<BB * 2, 256, 0, stream>>>(b2, W3, b3, fw, wsf, out1, out, nullptr);
}